// Round 3
// baseline (253.345 us; speedup 1.0000x reference)
//
#include <hip/hip_runtime.h>
#include <hip/hip_bf16.h>

// Problem constants
#define NN     8192      // nodes
#define D0     512       // x feature dim
#define D1     256       // hidden dim (W1 out)
#define D2     64        // z dim (W2 out)
#define NE     262144    // edges

typedef __attribute__((ext_vector_type(8)))  __bf16 bf16x8;
typedef __attribute__((ext_vector_type(16))) float  f32x16;

// ---------------------------------------------------------------------------
// Convert x (fp32) -> xh, xl (bf16 hi/lo split), row-major [8192][512]
// ---------------------------------------------------------------------------
__global__ __launch_bounds__(256) void convx_k(const float* __restrict__ X,
                                               __bf16* __restrict__ Xh,
                                               __bf16* __restrict__ Xl) {
    const int i = blockIdx.x * 256 + threadIdx.x;   // unit of 8 floats
    float4 v0 = reinterpret_cast<const float4*>(X)[i * 2 + 0];
    float4 v1 = reinterpret_cast<const float4*>(X)[i * 2 + 1];
    float f[8] = {v0.x, v0.y, v0.z, v0.w, v1.x, v1.y, v1.z, v1.w};
    bf16x8 h, l;
    #pragma unroll
    for (int j = 0; j < 8; ++j) {
        __bf16 hj = (__bf16)f[j];
        h[j] = hj;
        l[j] = (__bf16)(f[j] - (float)hj);
    }
    reinterpret_cast<bf16x8*>(Xh)[i] = h;
    reinterpret_cast<bf16x8*>(Xl)[i] = l;
}

// ---------------------------------------------------------------------------
// Convert W1 [512][256] fp32 -> transposed bf16 hi/lo: W1T[256][512]
// 32x32 tiles via LDS
// ---------------------------------------------------------------------------
__global__ __launch_bounds__(256) void convw1t_k(const float* __restrict__ W,
                                                 __bf16* __restrict__ Th,
                                                 __bf16* __restrict__ Tl) {
    __shared__ float t[32][33];
    const int k0 = blockIdx.y * 32;
    const int c0 = blockIdx.x * 32;
    {
        int tr  = threadIdx.x >> 3;        // 0..31 (k row)
        int tc4 = threadIdx.x & 7;         // 0..7  (4 cols each)
        float4 v = *reinterpret_cast<const float4*>(&W[(k0 + tr) * D1 + c0 + tc4 * 4]);
        t[tr][tc4 * 4 + 0] = v.x;
        t[tr][tc4 * 4 + 1] = v.y;
        t[tr][tc4 * 4 + 2] = v.z;
        t[tr][tc4 * 4 + 3] = v.w;
    }
    __syncthreads();
    int c  = threadIdx.x >> 3;             // 0..31 (col -> out row)
    int kq = (threadIdx.x & 7) * 4;        // 4 k's each
    __bf16 hv[4], lv[4];
    #pragma unroll
    for (int j = 0; j < 4; ++j) {
        float f = t[kq + j][c];
        hv[j] = (__bf16)f;
        lv[j] = (__bf16)(f - (float)hv[j]);
    }
    *reinterpret_cast<uint2*>(&Th[(size_t)(c0 + c) * D0 + k0 + kq]) = *reinterpret_cast<uint2*>(hv);
    *reinterpret_cast<uint2*>(&Tl[(size_t)(c0 + c) * D0 + k0 + kq]) = *reinterpret_cast<uint2*>(lv);
}

// ---------------------------------------------------------------------------
// GEMM1 via bf16 MFMA hi/lo split: xw1 = x @ W1  (fp32-equivalent accuracy)
//   xw1 ~= xh@wh + xh@wl + xl@wh
// No LDS: direct bf16x8 global loads (L2/L3 resident operands).
// Block 256 thr = 4 waves (2x2), wave = 32x32, grid (128, 4).
// A-frag: lane holds X[rowBase + (lane&31)][k0 + (lane>>5)*8 + e]
// B-frag: lane holds W1T[colBase + (lane&31)][k0 + (lane>>5)*8 + e]
// C/D:    col=lane&31, row=(reg&3)+8*(reg>>2)+4*(lane>>5)
// ---------------------------------------------------------------------------
__global__ __launch_bounds__(256) void gemm1_mfma_k(const __bf16* __restrict__ Xh,
                                                    const __bf16* __restrict__ Xl,
                                                    const __bf16* __restrict__ Wh,
                                                    const __bf16* __restrict__ Wl,
                                                    float* __restrict__ O) {
    const int tid  = threadIdx.x;
    const int lane = tid & 63;
    const int w    = tid >> 6;
    const int wm   = w >> 1;
    const int wn   = w & 1;
    const int r32  = lane & 31;
    const int kh   = lane >> 5;
    const int row  = blockIdx.x * 64 + wm * 32 + r32;
    const int col  = blockIdx.y * 64 + wn * 32 + r32;

    const __bf16* pAh = Xh + (size_t)row * D0;
    const __bf16* pAl = Xl + (size_t)row * D0;
    const __bf16* pBh = Wh + (size_t)col * D0;
    const __bf16* pBl = Wl + (size_t)col * D0;

    f32x16 acc = {};
    #pragma unroll 8
    for (int k0 = 0; k0 < D0; k0 += 16) {
        const int koff = k0 + kh * 8;
        bf16x8 ah = *reinterpret_cast<const bf16x8*>(pAh + koff);
        bf16x8 al = *reinterpret_cast<const bf16x8*>(pAl + koff);
        bf16x8 bh = *reinterpret_cast<const bf16x8*>(pBh + koff);
        bf16x8 bl = *reinterpret_cast<const bf16x8*>(pBl + koff);
        acc = __builtin_amdgcn_mfma_f32_32x32x16_bf16(ah, bh, acc, 0, 0, 0);
        acc = __builtin_amdgcn_mfma_f32_32x32x16_bf16(ah, bl, acc, 0, 0, 0);
        acc = __builtin_amdgcn_mfma_f32_32x32x16_bf16(al, bh, acc, 0, 0, 0);
    }

    const int rowBase = blockIdx.x * 64 + wm * 32;
    const int colBase = blockIdx.y * 64 + wn * 32;
    #pragma unroll
    for (int reg = 0; reg < 16; ++reg) {
        int r = (reg & 3) + 8 * (reg >> 2) + 4 * kh;
        O[(size_t)(rowBase + r) * D1 + colBase + r32] = acc[reg];
    }
}

// ---------------------------------------------------------------------------
// zero cnt+cur: 4096 x int4 = 64KB
// ---------------------------------------------------------------------------
__global__ __launch_bounds__(256) void zero_k(int4* __restrict__ p) {
    p[blockIdx.x * 256 + threadIdx.x] = make_int4(0, 0, 0, 0);
}

// ---------------------------------------------------------------------------
// CSR build
// ---------------------------------------------------------------------------
__global__ __launch_bounds__(256) void hist_k(const int* __restrict__ dst,
                                              int* __restrict__ counts) {
    int i = blockIdx.x * 256 + threadIdx.x;
    if (i < NE) atomicAdd(&counts[dst[i]], 1);
}

// shuffle-based scan: 256 threads x 32 counts each
__global__ __launch_bounds__(256) void scan_k(const int* __restrict__ counts,
                                              int* __restrict__ rs) {
    __shared__ int wsum[4];
    const int tid  = threadIdx.x;
    const int base = tid * 32;
    int v[32];
    int s = 0;
    #pragma unroll
    for (int j = 0; j < 8; ++j) {
        int4 q = reinterpret_cast<const int4*>(&counts[base])[j];
        v[j * 4 + 0] = q.x; v[j * 4 + 1] = q.y; v[j * 4 + 2] = q.z; v[j * 4 + 3] = q.w;
        s += q.x + q.y + q.z + q.w;
    }
    int inc = s;
    #pragma unroll
    for (int off = 1; off < 64; off <<= 1) {
        int t = __shfl_up(inc, off, 64);
        if ((tid & 63) >= off) inc += t;
    }
    if ((tid & 63) == 63) wsum[tid >> 6] = inc;
    __syncthreads();
    int wpre = 0;
    #pragma unroll
    for (int wi = 0; wi < 4; ++wi) if (wi < (tid >> 6)) wpre += wsum[wi];
    int ex = wpre + inc - s;
    #pragma unroll
    for (int j = 0; j < 32; ++j) { rs[base + j] = ex; ex += v[j]; }
    if (tid == 0) rs[NN] = NE;
}

__global__ __launch_bounds__(256) void scatter_k(const int* __restrict__ src,
                                                 const int* __restrict__ dst,
                                                 const float* __restrict__ w,
                                                 const int* __restrict__ rs,
                                                 int* __restrict__ cursor,
                                                 int* __restrict__ eps,
                                                 float* __restrict__ epw) {
    int i = blockIdx.x * 256 + threadIdx.x;
    if (i < NE) {
        int d = dst[i];
        int pos = rs[d] + atomicAdd(&cursor[d], 1);
        eps[pos] = src[i];
        epw[pos] = w[i];
    }
}

// ---------------------------------------------------------------------------
// SPMM layer 1 + relu — column-split x2 so the gathered working set (4MB)
// fits a per-XCD L2. grid (NN, 2), block 128.
// ---------------------------------------------------------------------------
__global__ __launch_bounds__(128) void spmm_relu_k(const float* __restrict__ Hin,
                                                   const int* __restrict__ rs,
                                                   const int* __restrict__ eps,
                                                   const float* __restrict__ epw,
                                                   float* __restrict__ Hout) {
    const int row = blockIdx.x;
    const int c   = (blockIdx.y << 7) + threadIdx.x;
    const int start = rs[row], end = rs[row + 1];
    float acc = 0.f;
    for (int j = start; j < end; ++j) {
        acc += epw[j] * Hin[(size_t)eps[j] * D1 + c];
    }
    Hout[(size_t)row * D1 + c] = fmaxf(acc, 0.f);
}

// ---------------------------------------------------------------------------
// GEMM2: h1w2 = h1 @ W2
// ---------------------------------------------------------------------------
__global__ __launch_bounds__(256) void gemm_h1w2_k(const float* __restrict__ H,
                                                   const float* __restrict__ W,
                                                   float* __restrict__ O) {
    __shared__ __align__(16) float hs[4][D1];
    const int tid = threadIdx.x;
    const int r = tid >> 6;
    const int c = tid & 63;
    const int row0 = blockIdx.x * 4;
    {
        int lr = tid >> 6, lc4 = tid & 63;
        *reinterpret_cast<float4*>(&hs[lr][lc4 * 4]) =
            *reinterpret_cast<const float4*>(&H[(row0 + lr) * D1 + lc4 * 4]);
    }
    __syncthreads();
    float acc = 0.f;
    #pragma unroll 8
    for (int k = 0; k < D1; ++k) acc += hs[r][k] * W[k * D2 + c];
    O[(row0 + r) * D2 + c] = acc;
}

// ---------------------------------------------------------------------------
// SPMM layer 2: emits z split into hi/lo bf16 directly.
// ---------------------------------------------------------------------------
__global__ __launch_bounds__(256) void spmm64_k(const float* __restrict__ Hin,
                                                const int* __restrict__ rs,
                                                const int* __restrict__ eps,
                                                const float* __restrict__ epw,
                                                __bf16* __restrict__ Zh,
                                                __bf16* __restrict__ Zl) {
    const int row = blockIdx.x * 4 + (threadIdx.x >> 6);
    const int c = threadIdx.x & 63;
    const int start = rs[row], end = rs[row + 1];
    float acc = 0.f;
    for (int j = start; j < end; ++j) {
        acc += epw[j] * Hin[eps[j] * D2 + c];
    }
    __bf16 h = (__bf16)acc;
    Zh[row * D2 + c] = h;
    Zl[row * D2 + c] = (__bf16)(acc - (float)h);
}

// ---------------------------------------------------------------------------
// ZZT via bf16 MFMA hi/lo split (passed validation in R2):
//   out = zh@zh^T + zh@zl^T + zl@zh^T
// ---------------------------------------------------------------------------
__global__ __launch_bounds__(256) void zzt_k(const __bf16* __restrict__ Zh,
                                             const __bf16* __restrict__ Zl,
                                             float* __restrict__ O) {
    const int tid  = threadIdx.x;
    const int lane = tid & 63;
    const int w    = tid >> 6;
    const int wm   = w >> 1;
    const int wn   = w & 1;
    const int r32  = lane & 31;
    const int kh   = lane >> 5;
    const int rowBase = blockIdx.y * 128 + wm * 64;
    const int colBase = blockIdx.x * 128 + wn * 64;

    f32x16 acc[2][2] = {};

    #pragma unroll
    for (int kk = 0; kk < 4; ++kk) {
        const int koff = kk * 16 + kh * 8;
        bf16x8 ah0 = *reinterpret_cast<const bf16x8*>(&Zh[(rowBase +      r32) * D2 + koff]);
        bf16x8 ah1 = *reinterpret_cast<const bf16x8*>(&Zh[(rowBase + 32 + r32) * D2 + koff]);
        bf16x8 al0 = *reinterpret_cast<const bf16x8*>(&Zl[(rowBase +      r32) * D2 + koff]);
        bf16x8 al1 = *reinterpret_cast<const bf16x8*>(&Zl[(rowBase + 32 + r32) * D2 + koff]);
        bf16x8 bh0 = *reinterpret_cast<const bf16x8*>(&Zh[(colBase +      r32) * D2 + koff]);
        bf16x8 bh1 = *reinterpret_cast<const bf16x8*>(&Zh[(colBase + 32 + r32) * D2 + koff]);
        bf16x8 bl0 = *reinterpret_cast<const bf16x8*>(&Zl[(colBase +      r32) * D2 + koff]);
        bf16x8 bl1 = *reinterpret_cast<const bf16x8*>(&Zl[(colBase + 32 + r32) * D2 + koff]);

        acc[0][0] = __builtin_amdgcn_mfma_f32_32x32x16_bf16(ah0, bh0, acc[0][0], 0, 0, 0);
        acc[0][1] = __builtin_amdgcn_mfma_f32_32x32x16_bf16(ah0, bh1, acc[0][1], 0, 0, 0);
        acc[1][0] = __builtin_amdgcn_mfma_f32_32x32x16_bf16(ah1, bh0, acc[1][0], 0, 0, 0);
        acc[1][1] = __builtin_amdgcn_mfma_f32_32x32x16_bf16(ah1, bh1, acc[1][1], 0, 0, 0);

        acc[0][0] = __builtin_amdgcn_mfma_f32_32x32x16_bf16(ah0, bl0, acc[0][0], 0, 0, 0);
        acc[0][1] = __builtin_amdgcn_mfma_f32_32x32x16_bf16(ah0, bl1, acc[0][1], 0, 0, 0);
        acc[1][0] = __builtin_amdgcn_mfma_f32_32x32x16_bf16(ah1, bl0, acc[1][0], 0, 0, 0);
        acc[1][1] = __builtin_amdgcn_mfma_f32_32x32x16_bf16(ah1, bl1, acc[1][1], 0, 0, 0);

        acc[0][0] = __builtin_amdgcn_mfma_f32_32x32x16_bf16(al0, bh0, acc[0][0], 0, 0, 0);
        acc[0][1] = __builtin_amdgcn_mfma_f32_32x32x16_bf16(al0, bh1, acc[0][1], 0, 0, 0);
        acc[1][0] = __builtin_amdgcn_mfma_f32_32x32x16_bf16(al1, bh0, acc[1][0], 0, 0, 0);
        acc[1][1] = __builtin_amdgcn_mfma_f32_32x32x16_bf16(al1, bh1, acc[1][1], 0, 0, 0);
    }

    #pragma unroll
    for (int i = 0; i < 2; ++i)
        #pragma unroll
        for (int j = 0; j < 2; ++j)
            #pragma unroll
            for (int reg = 0; reg < 16; ++reg) {
                int r = (reg & 3) + 8 * (reg >> 2) + 4 * kh;
                O[(size_t)(rowBase + i * 32 + r) * NN + colBase + j * 32 + r32] = acc[i][j][reg];
            }
}

// ---------------------------------------------------------------------------
// Launch
// ---------------------------------------------------------------------------
extern "C" void kernel_launch(void* const* d_in, const int* in_sizes, int n_in,
                              void* d_out, int out_size, void* d_ws, size_t ws_size,
                              hipStream_t stream) {
    const float* x        = (const float*)d_in[0];
    const int*   edge_src = (const int*)d_in[1];
    const int*   edge_dst = (const int*)d_in[2];
    const float* edge_w   = (const float*)d_in[3];
    const float* W1       = (const float*)d_in[4];
    const float* W2       = (const float*)d_in[5];
    float* out = (float*)d_out;

    char* ws = (char*)d_ws;
    const size_t OFF_XW1  = 0;                                  // 8 MB
    const size_t OFF_H1   = OFF_XW1  + (size_t)NN * D1 * 4;     // 8 MB
    const size_t OFF_H1W2 = OFF_H1   + (size_t)NN * D1 * 4;     // 2 MB
    const size_t OFF_ZH   = OFF_H1W2 + (size_t)NN * D2 * 4;     // 1 MB
    const size_t OFF_ZL   = OFF_ZH   + (size_t)NN * D2 * 2;     // 1 MB
    const size_t OFF_XH   = OFF_ZL   + (size_t)NN * D2 * 2;     // 8 MB
    const size_t OFF_XL   = OFF_XH   + (size_t)NN * D0 * 2;     // 8 MB
    const size_t OFF_WTH  = OFF_XL   + (size_t)NN * D0 * 2;     // 512 KB
    const size_t OFF_WTL  = OFF_WTH  + (size_t)D0 * D1 * 2;     // 512 KB
    const size_t OFF_RS   = OFF_WTL  + (size_t)D0 * D1 * 2;     // (NN+1) ints
    const size_t OFF_CNT  = OFF_RS   + 33280;                   // NN ints
    const size_t OFF_CUR  = OFF_CNT  + (size_t)NN * 4;          // NN ints
    const size_t OFF_EPS  = OFF_CUR  + (size_t)NN * 4;          // NE ints
    const size_t OFF_EPW  = OFF_EPS  + (size_t)NE * 4;          // NE floats

    float*  xw1  = (float*)(ws + OFF_XW1);
    float*  h1   = (float*)(ws + OFF_H1);
    float*  h1w2 = (float*)(ws + OFF_H1W2);
    __bf16* zh   = (__bf16*)(ws + OFF_ZH);
    __bf16* zl   = (__bf16*)(ws + OFF_ZL);
    __bf16* xh   = (__bf16*)(ws + OFF_XH);
    __bf16* xl   = (__bf16*)(ws + OFF_XL);
    __bf16* wth  = (__bf16*)(ws + OFF_WTH);
    __bf16* wtl  = (__bf16*)(ws + OFF_WTL);
    int*    rs   = (int*)(ws + OFF_RS);
    int*    cnt  = (int*)(ws + OFF_CNT);
    int*    cur  = (int*)(ws + OFF_CUR);
    int*    eps  = (int*)(ws + OFF_EPS);
    float*  epw  = (float*)(ws + OFF_EPW);

    zero_k<<<16, 256, 0, stream>>>((int4*)cnt);

    // x/W1 -> bf16 hi/lo, W1 transposed
    convx_k<<<(NN * D0 / 8) / 256, 256, 0, stream>>>(x, xh, xl);
    convw1t_k<<<dim3(D1 / 32, D0 / 32), 256, 0, stream>>>(W1, wth, wtl);

    // GEMM1 via MFMA split
    gemm1_mfma_k<<<dim3(NN / 64, D1 / 64), 256, 0, stream>>>(xh, xl, wth, wtl, xw1);

    // CSR build
    hist_k<<<NE / 256, 256, 0, stream>>>(edge_dst, cnt);
    scan_k<<<1, 256, 0, stream>>>(cnt, rs);
    scatter_k<<<NE / 256, 256, 0, stream>>>(edge_src, edge_dst, edge_w, rs, cur, eps, epw);

    // SPMM1 + relu (column-split x2 for L2 residency)
    spmm_relu_k<<<dim3(NN, 2), 128, 0, stream>>>(xw1, rs, eps, epw, h1);

    // GEMM2
    gemm_h1w2_k<<<NN / 4, 256, 0, stream>>>(h1, W2, h1w2);

    // SPMM2 -> zh/zl
    spmm64_k<<<NN / 4, 256, 0, stream>>>(h1w2, rs, eps, epw, zh, zl);

    // recon = z @ z^T
    zzt_k<<<dim3(NN / 128, NN / 128), 256, 0, stream>>>(zh, zl, out);
}

// Round 4
// 235.384 us; speedup vs baseline: 1.0763x; 1.0763x over previous
//
#include <hip/hip_runtime.h>
#include <hip/hip_bf16.h>

// Problem constants
#define NN     8192      // nodes
#define D0     512       // x feature dim
#define D1     256       // hidden dim (W1 out)
#define D2     64        // z dim (W2 out)
#define NE     262144    // edges

typedef __attribute__((ext_vector_type(8)))  __bf16 bf16x8;
typedef __attribute__((ext_vector_type(16))) float  f32x16;

// ---------------------------------------------------------------------------
// prep_k: fused  zero(cnt,cur) + convx (x->xh,xl) + convw1t (W1 -> W1T hi/lo)
// grid = 16 + 2048 + 128 blocks, 256 threads
// ---------------------------------------------------------------------------
__global__ __launch_bounds__(256) void prep_k(const float* __restrict__ X,
                                              const float* __restrict__ W,
                                              int4* __restrict__ zero_region,
                                              __bf16* __restrict__ Xh,
                                              __bf16* __restrict__ Xl,
                                              __bf16* __restrict__ Th,
                                              __bf16* __restrict__ Tl) {
    const int bid = blockIdx.x;
    const int tid = threadIdx.x;
    if (bid < 16) {
        // zero cnt+cur: 16*256 int4 = 64KB
        zero_region[bid * 256 + tid] = make_int4(0, 0, 0, 0);
    } else if (bid < 16 + 2048) {
        // convx: unit of 8 floats
        const int i = (bid - 16) * 256 + tid;
        float4 v0 = reinterpret_cast<const float4*>(X)[i * 2 + 0];
        float4 v1 = reinterpret_cast<const float4*>(X)[i * 2 + 1];
        float f[8] = {v0.x, v0.y, v0.z, v0.w, v1.x, v1.y, v1.z, v1.w};
        bf16x8 h, l;
        #pragma unroll
        for (int j = 0; j < 8; ++j) {
            __bf16 hj = (__bf16)f[j];
            h[j] = hj;
            l[j] = (__bf16)(f[j] - (float)hj);
        }
        reinterpret_cast<bf16x8*>(Xh)[i] = h;
        reinterpret_cast<bf16x8*>(Xl)[i] = l;
    } else {
        // convw1t: 128 blocks, 32x32 tile transpose via LDS
        __shared__ float t[32][33];
        const int cid = bid - 16 - 2048;
        const int c0 = (cid & 7) * 32;      // D1/32 = 8
        const int k0 = (cid >> 3) * 32;     // D0/32 = 16
        {
            int tr  = tid >> 3;
            int tc4 = tid & 7;
            float4 v = *reinterpret_cast<const float4*>(&W[(k0 + tr) * D1 + c0 + tc4 * 4]);
            t[tr][tc4 * 4 + 0] = v.x;
            t[tr][tc4 * 4 + 1] = v.y;
            t[tr][tc4 * 4 + 2] = v.z;
            t[tr][tc4 * 4 + 3] = v.w;
        }
        __syncthreads();
        int c  = tid >> 3;
        int kq = (tid & 7) * 4;
        __bf16 hv[4], lv[4];
        #pragma unroll
        for (int j = 0; j < 4; ++j) {
            float f = t[kq + j][c];
            hv[j] = (__bf16)f;
            lv[j] = (__bf16)(f - (float)hv[j]);
        }
        *reinterpret_cast<uint2*>(&Th[(size_t)(c0 + c) * D0 + k0 + kq]) = *reinterpret_cast<uint2*>(hv);
        *reinterpret_cast<uint2*>(&Tl[(size_t)(c0 + c) * D0 + k0 + kq]) = *reinterpret_cast<uint2*>(lv);
    }
}

// ---------------------------------------------------------------------------
// GEMM1 via bf16 MFMA hi/lo split: xw1 = x @ W1
// Block 256 thr = 4 waves (2x2), wave = 32x32, grid (128, 4).
// ---------------------------------------------------------------------------
__global__ __launch_bounds__(256) void gemm1_mfma_k(const __bf16* __restrict__ Xh,
                                                    const __bf16* __restrict__ Xl,
                                                    const __bf16* __restrict__ Wh,
                                                    const __bf16* __restrict__ Wl,
                                                    float* __restrict__ O) {
    const int tid  = threadIdx.x;
    const int lane = tid & 63;
    const int w    = tid >> 6;
    const int wm   = w >> 1;
    const int wn   = w & 1;
    const int r32  = lane & 31;
    const int kh   = lane >> 5;
    const int row  = blockIdx.x * 64 + wm * 32 + r32;
    const int col  = blockIdx.y * 64 + wn * 32 + r32;

    const __bf16* pAh = Xh + (size_t)row * D0;
    const __bf16* pAl = Xl + (size_t)row * D0;
    const __bf16* pBh = Wh + (size_t)col * D0;
    const __bf16* pBl = Wl + (size_t)col * D0;

    f32x16 acc = {};
    #pragma unroll 8
    for (int k0 = 0; k0 < D0; k0 += 16) {
        const int koff = k0 + kh * 8;
        bf16x8 ah = *reinterpret_cast<const bf16x8*>(pAh + koff);
        bf16x8 al = *reinterpret_cast<const bf16x8*>(pAl + koff);
        bf16x8 bh = *reinterpret_cast<const bf16x8*>(pBh + koff);
        bf16x8 bl = *reinterpret_cast<const bf16x8*>(pBl + koff);
        acc = __builtin_amdgcn_mfma_f32_32x32x16_bf16(ah, bh, acc, 0, 0, 0);
        acc = __builtin_amdgcn_mfma_f32_32x32x16_bf16(ah, bl, acc, 0, 0, 0);
        acc = __builtin_amdgcn_mfma_f32_32x32x16_bf16(al, bh, acc, 0, 0, 0);
    }

    const int rowBase = blockIdx.x * 64 + wm * 32;
    const int colBase = blockIdx.y * 64 + wn * 32;
    #pragma unroll
    for (int reg = 0; reg < 16; ++reg) {
        int r = (reg & 3) + 8 * (reg >> 2) + 4 * kh;
        O[(size_t)(rowBase + r) * D1 + colBase + r32] = acc[reg];
    }
}

// ---------------------------------------------------------------------------
// CSR build
// ---------------------------------------------------------------------------
__global__ __launch_bounds__(256) void hist_k(const int* __restrict__ dst,
                                              int* __restrict__ counts) {
    int i = blockIdx.x * 256 + threadIdx.x;
    if (i < NE) atomicAdd(&counts[dst[i]], 1);
}

// shuffle-based scan: 256 threads x 32 counts each
__global__ __launch_bounds__(256) void scan_k(const int* __restrict__ counts,
                                              int* __restrict__ rs) {
    __shared__ int wsum[4];
    const int tid  = threadIdx.x;
    const int base = tid * 32;
    int v[32];
    int s = 0;
    #pragma unroll
    for (int j = 0; j < 8; ++j) {
        int4 q = reinterpret_cast<const int4*>(&counts[base])[j];
        v[j * 4 + 0] = q.x; v[j * 4 + 1] = q.y; v[j * 4 + 2] = q.z; v[j * 4 + 3] = q.w;
        s += q.x + q.y + q.z + q.w;
    }
    int inc = s;
    #pragma unroll
    for (int off = 1; off < 64; off <<= 1) {
        int t = __shfl_up(inc, off, 64);
        if ((tid & 63) >= off) inc += t;
    }
    if ((tid & 63) == 63) wsum[tid >> 6] = inc;
    __syncthreads();
    int wpre = 0;
    #pragma unroll
    for (int wi = 0; wi < 4; ++wi) if (wi < (tid >> 6)) wpre += wsum[wi];
    int ex = wpre + inc - s;
    #pragma unroll
    for (int j = 0; j < 32; ++j) { rs[base + j] = ex; ex += v[j]; }
    if (tid == 0) rs[NN] = NE;
}

__global__ __launch_bounds__(256) void scatter_k(const int* __restrict__ src,
                                                 const int* __restrict__ dst,
                                                 const float* __restrict__ w,
                                                 const int* __restrict__ rs,
                                                 int* __restrict__ cursor,
                                                 int* __restrict__ eps,
                                                 float* __restrict__ epw) {
    int i = blockIdx.x * 256 + threadIdx.x;
    if (i < NE) {
        int d = dst[i];
        int pos = rs[d] + atomicAdd(&cursor[d], 1);
        eps[pos] = src[i];
        epw[pos] = w[i];
    }
}

// ---------------------------------------------------------------------------
// Fused SPMM1 + relu + GEMM2:
//   h1row = relu( sum_e w_e * xw1[src_e][:] )     (256 cols, in LDS)
//   h1w2[row][c] = dot(h1row, W2[:,c])            (64 cols)
// One block (256 thr) per dst row. Eliminates the 8MB h1 round-trip.
// ---------------------------------------------------------------------------
__global__ __launch_bounds__(256) void spmmfuse_k(const float* __restrict__ Hin,
                                                  const int* __restrict__ rs,
                                                  const int* __restrict__ eps,
                                                  const float* __restrict__ epw,
                                                  const float* __restrict__ W2,
                                                  float* __restrict__ H1W2) {
    __shared__ float h1row[D1];
    const int row = blockIdx.x;
    const int tid = threadIdx.x;
    const int start = rs[row], end = rs[row + 1];
    float acc = 0.f;
    for (int j = start; j < end; ++j) {
        acc += epw[j] * Hin[(size_t)eps[j] * D1 + tid];
    }
    h1row[tid] = fmaxf(acc, 0.f);
    __syncthreads();
    if (tid < D2) {
        float o = 0.f;
        #pragma unroll 16
        for (int k = 0; k < D1; ++k) o += h1row[k] * W2[k * D2 + tid];
        H1W2[(size_t)row * D2 + tid] = o;
    }
}

// ---------------------------------------------------------------------------
// SPMM layer 2: emits z split into hi/lo bf16 directly.
// ---------------------------------------------------------------------------
__global__ __launch_bounds__(256) void spmm64_k(const float* __restrict__ Hin,
                                                const int* __restrict__ rs,
                                                const int* __restrict__ eps,
                                                const float* __restrict__ epw,
                                                __bf16* __restrict__ Zh,
                                                __bf16* __restrict__ Zl) {
    const int row = blockIdx.x * 4 + (threadIdx.x >> 6);
    const int c = threadIdx.x & 63;
    const int start = rs[row], end = rs[row + 1];
    float acc = 0.f;
    for (int j = start; j < end; ++j) {
        acc += epw[j] * Hin[eps[j] * D2 + c];
    }
    __bf16 h = (__bf16)acc;
    Zh[row * D2 + c] = h;
    Zl[row * D2 + c] = (__bf16)(acc - (float)h);
}

// ---------------------------------------------------------------------------
// ZZT via bf16 MFMA hi/lo split:  out = zh@zh^T + zh@zl^T + zl@zh^T
// Non-temporal stores: 256MB write-once output, keep L2 for operands.
// ---------------------------------------------------------------------------
__global__ __launch_bounds__(256) void zzt_k(const __bf16* __restrict__ Zh,
                                             const __bf16* __restrict__ Zl,
                                             float* __restrict__ O) {
    const int tid  = threadIdx.x;
    const int lane = tid & 63;
    const int w    = tid >> 6;
    const int wm   = w >> 1;
    const int wn   = w & 1;
    const int r32  = lane & 31;
    const int kh   = lane >> 5;
    const int rowBase = blockIdx.y * 128 + wm * 64;
    const int colBase = blockIdx.x * 128 + wn * 64;

    f32x16 acc[2][2] = {};

    #pragma unroll
    for (int kk = 0; kk < 4; ++kk) {
        const int koff = kk * 16 + kh * 8;
        bf16x8 ah0 = *reinterpret_cast<const bf16x8*>(&Zh[(rowBase +      r32) * D2 + koff]);
        bf16x8 ah1 = *reinterpret_cast<const bf16x8*>(&Zh[(rowBase + 32 + r32) * D2 + koff]);
        bf16x8 al0 = *reinterpret_cast<const bf16x8*>(&Zl[(rowBase +      r32) * D2 + koff]);
        bf16x8 al1 = *reinterpret_cast<const bf16x8*>(&Zl[(rowBase + 32 + r32) * D2 + koff]);
        bf16x8 bh0 = *reinterpret_cast<const bf16x8*>(&Zh[(colBase +      r32) * D2 + koff]);
        bf16x8 bh1 = *reinterpret_cast<const bf16x8*>(&Zh[(colBase + 32 + r32) * D2 + koff]);
        bf16x8 bl0 = *reinterpret_cast<const bf16x8*>(&Zl[(colBase +      r32) * D2 + koff]);
        bf16x8 bl1 = *reinterpret_cast<const bf16x8*>(&Zl[(colBase + 32 + r32) * D2 + koff]);

        acc[0][0] = __builtin_amdgcn_mfma_f32_32x32x16_bf16(ah0, bh0, acc[0][0], 0, 0, 0);
        acc[0][1] = __builtin_amdgcn_mfma_f32_32x32x16_bf16(ah0, bh1, acc[0][1], 0, 0, 0);
        acc[1][0] = __builtin_amdgcn_mfma_f32_32x32x16_bf16(ah1, bh0, acc[1][0], 0, 0, 0);
        acc[1][1] = __builtin_amdgcn_mfma_f32_32x32x16_bf16(ah1, bh1, acc[1][1], 0, 0, 0);

        acc[0][0] = __builtin_amdgcn_mfma_f32_32x32x16_bf16(ah0, bl0, acc[0][0], 0, 0, 0);
        acc[0][1] = __builtin_amdgcn_mfma_f32_32x32x16_bf16(ah0, bl1, acc[0][1], 0, 0, 0);
        acc[1][0] = __builtin_amdgcn_mfma_f32_32x32x16_bf16(ah1, bl0, acc[1][0], 0, 0, 0);
        acc[1][1] = __builtin_amdgcn_mfma_f32_32x32x16_bf16(ah1, bl1, acc[1][1], 0, 0, 0);

        acc[0][0] = __builtin_amdgcn_mfma_f32_32x32x16_bf16(al0, bh0, acc[0][0], 0, 0, 0);
        acc[0][1] = __builtin_amdgcn_mfma_f32_32x32x16_bf16(al0, bh1, acc[0][1], 0, 0, 0);
        acc[1][0] = __builtin_amdgcn_mfma_f32_32x32x16_bf16(al1, bh0, acc[1][0], 0, 0, 0);
        acc[1][1] = __builtin_amdgcn_mfma_f32_32x32x16_bf16(al1, bh1, acc[1][1], 0, 0, 0);
    }

    #pragma unroll
    for (int i = 0; i < 2; ++i)
        #pragma unroll
        for (int j = 0; j < 2; ++j)
            #pragma unroll
            for (int reg = 0; reg < 16; ++reg) {
                int r = (reg & 3) + 8 * (reg >> 2) + 4 * kh;
                __builtin_nontemporal_store(acc[i][j][reg],
                    &O[(size_t)(rowBase + i * 32 + r) * NN + colBase + j * 32 + r32]);
            }
}

// ---------------------------------------------------------------------------
// Launch
// ---------------------------------------------------------------------------
extern "C" void kernel_launch(void* const* d_in, const int* in_sizes, int n_in,
                              void* d_out, int out_size, void* d_ws, size_t ws_size,
                              hipStream_t stream) {
    const float* x        = (const float*)d_in[0];
    const int*   edge_src = (const int*)d_in[1];
    const int*   edge_dst = (const int*)d_in[2];
    const float* edge_w   = (const float*)d_in[3];
    const float* W1       = (const float*)d_in[4];
    const float* W2       = (const float*)d_in[5];
    float* out = (float*)d_out;

    char* ws = (char*)d_ws;
    const size_t OFF_XW1  = 0;                                  // 8 MB
    const size_t OFF_H1W2 = OFF_XW1  + (size_t)NN * D1 * 4;     // 2 MB
    const size_t OFF_ZH   = OFF_H1W2 + (size_t)NN * D2 * 4;     // 1 MB
    const size_t OFF_ZL   = OFF_ZH   + (size_t)NN * D2 * 2;     // 1 MB
    const size_t OFF_XH   = OFF_ZL   + (size_t)NN * D2 * 2;     // 8 MB
    const size_t OFF_XL   = OFF_XH   + (size_t)NN * D0 * 2;     // 8 MB
    const size_t OFF_WTH  = OFF_XL   + (size_t)NN * D0 * 2;     // 512 KB
    const size_t OFF_WTL  = OFF_WTH  + (size_t)D0 * D1 * 2;     // 512 KB
    const size_t OFF_RS   = OFF_WTL  + (size_t)D0 * D1 * 2;     // (NN+1) ints
    const size_t OFF_CNT  = OFF_RS   + 33280;                   // NN ints (zeroed)
    const size_t OFF_CUR  = OFF_CNT  + (size_t)NN * 4;          // NN ints (zeroed)
    const size_t OFF_EPS  = OFF_CUR  + (size_t)NN * 4;          // NE ints
    const size_t OFF_EPW  = OFF_EPS  + (size_t)NE * 4;          // NE floats

    float*  xw1  = (float*)(ws + OFF_XW1);
    float*  h1w2 = (float*)(ws + OFF_H1W2);
    __bf16* zh   = (__bf16*)(ws + OFF_ZH);
    __bf16* zl   = (__bf16*)(ws + OFF_ZL);
    __bf16* xh   = (__bf16*)(ws + OFF_XH);
    __bf16* xl   = (__bf16*)(ws + OFF_XL);
    __bf16* wth  = (__bf16*)(ws + OFF_WTH);
    __bf16* wtl  = (__bf16*)(ws + OFF_WTL);
    int*    rs   = (int*)(ws + OFF_RS);
    int*    cnt  = (int*)(ws + OFF_CNT);
    int*    eps  = (int*)(ws + OFF_EPS);
    float*  epw  = (float*)(ws + OFF_EPW);
    int*    cur  = (int*)(ws + OFF_CUR);

    // fused prep: zero(cnt+cur) + x->bf16 hi/lo + W1->W1T bf16 hi/lo
    prep_k<<<16 + 2048 + 128, 256, 0, stream>>>(x, W1, (int4*)cnt, xh, xl, wth, wtl);

    // GEMM1 via MFMA split
    gemm1_mfma_k<<<dim3(NN / 64, D1 / 64), 256, 0, stream>>>(xh, xl, wth, wtl, xw1);

    // CSR build
    hist_k<<<NE / 256, 256, 0, stream>>>(edge_dst, cnt);
    scan_k<<<1, 256, 0, stream>>>(cnt, rs);
    scatter_k<<<NE / 256, 256, 0, stream>>>(edge_src, edge_dst, edge_w, rs, cur, eps, epw);

    // fused SPMM1 + relu + GEMM2
    spmmfuse_k<<<NN, 256, 0, stream>>>(xw1, rs, eps, epw, W2, h1w2);

    // SPMM2 -> zh/zl
    spmm64_k<<<NN / 4, 256, 0, stream>>>(h1w2, rs, eps, epw, zh, zl);

    // recon = z @ z^T
    zzt_k<<<dim3(NN / 128, NN / 128), 256, 0, stream>>>(zh, zl, out);
}